// Round 2
// baseline (508.001 us; speedup 1.0000x reference)
//
#include <hip/hip_runtime.h>

#define B_N 131072
#define IN_N 40
#define P_N 128
#define H_N 256

typedef __bf16 bf16x8 __attribute__((ext_vector_type(8)));
typedef float f32x4 __attribute__((ext_vector_type(4)));

#define MFMA(a, b, c) __builtin_amdgcn_mfma_f32_16x16x32_bf16(a, b, c, 0, 0, 0)

__device__ __forceinline__ unsigned short f2bf(float f) {
  union { float f; unsigned u; } a; a.f = f;
  unsigned u = a.u;
  u += 0x7FFFu + ((u >> 16) & 1u);   // RNE
  return (unsigned short)(u >> 16);
}
__device__ __forceinline__ float bf2f(unsigned short h) {
  union { unsigned u; float f; } a; a.u = ((unsigned)h) << 16;
  return a.f;
}

// ws layout (ushort elements):
//   [0, 8192)            W_proj padded to [128][64] (cols 40..63 zero)
//   [8192, 106496)       W_ih  [768][128]
//   [106496, 303104)     W_hh  [768][256]
#define WS_WP 0
#define WS_WIH 8192
#define WS_WHH (8192 + 98304)
#define WS_TOT (8192 + 98304 + 196608)

// xp (bf16 x-projection, [B][128]) is stashed in the first 128 ushorts (=64
// floats) of each h_new row inside d_out. Each main-kernel block reads only
// its own 64 rows' xp and overwrites them after a barrier -> no cross-block
// hazard, no ws_size assumption.

__global__ void cvt_w(const float* __restrict__ Wp, const float* __restrict__ Wih,
                      const float* __restrict__ Whh, unsigned short* __restrict__ ws) {
  int i = blockIdx.x * 256 + threadIdx.x;
  if (i < 8192) {
    int r = i >> 6, c = i & 63;
    ws[i] = f2bf(c < IN_N ? Wp[r * IN_N + c] : 0.f);
  } else if (i < WS_WHH) {
    ws[i] = f2bf(Wih[i - WS_WIH]);
  } else if (i < WS_TOT) {
    ws[i] = f2bf(Whh[i - WS_WHH]);
  }
}

// x projection: 64 batch rows/block, 256 threads = 4 waves, wave owns 32 P cols.
__global__ __launch_bounds__(256, 4) void xproj(
    const float* __restrict__ x, const unsigned short* __restrict__ ws,
    const float* __restrict__ bp, float* out) {
  __shared__ unsigned short xs[64][72];
  const int tid = threadIdx.x;
  const int b0 = blockIdx.x * 64;
  const int lane = tid & 63;
  const int w = tid >> 6;
  const int l15 = lane & 15;
  const int l4 = lane >> 4;

  // stage x (bf16, zero-pad K 40->64). x tile is contiguous 64*40 floats.
  for (int i = tid; i < 64 * 24; i += 256) {  // zero pad cols 40..63
    int r = i / 24, c = 40 + i % 24;
    xs[r][c] = 0;
  }
  for (int i = tid; i < 64 * 40; i += 256) {
    int r = i / 40, c = i % 40;
    xs[r][c] = f2bf(x[(size_t)b0 * IN_N + i]);
  }
  __syncthreads();

  const int cb = w * 32;
  const int koff = l4 * 8;
  f32x4 acc[4][2] = {};
#pragma unroll
  for (int ks = 0; ks < 2; ++ks) {
    const int k = ks * 32 + koff;
    bf16x8 a[4];
#pragma unroll
    for (int mi = 0; mi < 4; ++mi)
      a[mi] = *reinterpret_cast<const bf16x8*>(&xs[mi * 16 + l15][k]);
#pragma unroll
    for (int ni = 0; ni < 2; ++ni) {
      const bf16x8 b = *reinterpret_cast<const bf16x8*>(&ws[WS_WP + (cb + ni * 16 + l15) * 64 + k]);
#pragma unroll
      for (int mi = 0; mi < 4; ++mi)
        acc[mi][ni] = MFMA(a[mi], b, acc[mi][ni]);
    }
  }
  unsigned short* xpd = (unsigned short*)out;  // ushort idx = 2*float idx
#pragma unroll
  for (int ni = 0; ni < 2; ++ni) {
    const int col = cb + ni * 16 + l15;
    const float bias = bp[col];
#pragma unroll
    for (int mi = 0; mi < 4; ++mi)
#pragma unroll
      for (int r = 0; r < 4; ++r) {
        const int row = b0 + mi * 16 + l4 * 4 + r;
        xpd[2 * (size_t)B_N + (size_t)row * 512 + col] = f2bf(acc[mi][ni][r] + bias);
      }
  }
}

// Main: 512 threads = 8 waves, 64 batch rows/block, wave owns 32 H cols.
__global__ __launch_bounds__(512, 4) void gru_main(
    const float* __restrict__ h0, const unsigned short* __restrict__ ws,
    const float* __restrict__ bih, const float* __restrict__ bhh,
    const float* __restrict__ Whead, const float* __restrict__ bhead,
    float* out) {
  __shared__ unsigned short hs[64][264];  // +8 pad: 2-way bank alias only (free)
  __shared__ float predp[8][64];

  const int tid = threadIdx.x;
  const int b0 = blockIdx.x * 64;
  const int lane = tid & 63;
  const int w = tid >> 6;
  const int l15 = lane & 15;
  const int l4 = lane >> 4;

  // stage h as bf16
  for (int i = tid; i < 64 * 64; i += 512) {
    int r = i >> 6, c4 = (i & 63) * 4;
    float4 v = *reinterpret_cast<const float4*>(&h0[(size_t)(b0 + r) * H_N + c4]);
    ushort4 u;
    u.x = f2bf(v.x); u.y = f2bf(v.y); u.z = f2bf(v.z); u.w = f2bf(v.w);
    *reinterpret_cast<ushort4*>(&hs[r][c4]) = u;
  }
  __syncthreads();

  const int cb = w * 32;
  const int koff = l4 * 8;
  f32x4 aR[4][2], aZ[4][2], aIN[4][2], aHN[4][2];
#pragma unroll
  for (int ni = 0; ni < 2; ++ni) {
    const int col = cb + ni * 16 + l15;
    const float vR = bih[col] + bhh[col];
    const float vZ = bih[H_N + col] + bhh[H_N + col];
    const float vIN = bih[2 * H_N + col];
    const float vHN = bhh[2 * H_N + col];
#pragma unroll
    for (int mi = 0; mi < 4; ++mi) {
      aR[mi][ni] = (f32x4){vR, vR, vR, vR};
      aZ[mi][ni] = (f32x4){vZ, vZ, vZ, vZ};
      aIN[mi][ni] = (f32x4){vIN, vIN, vIN, vIN};
      aHN[mi][ni] = (f32x4){vHN, vHN, vHN, vHN};
    }
  }

  const unsigned short* xp = (const unsigned short*)out + 2 * (size_t)B_N;

  // gi: K=128 over xp (global; 16KB tile shared by all 8 waves -> L1-hot)
#pragma unroll
  for (int ks = 0; ks < 4; ++ks) {
    const int k = ks * 32 + koff;
    bf16x8 a[4];
#pragma unroll
    for (int mi = 0; mi < 4; ++mi)
      a[mi] = *reinterpret_cast<const bf16x8*>(&xp[(size_t)(b0 + mi * 16 + l15) * 512 + k]);
#pragma unroll
    for (int ni = 0; ni < 2; ++ni) {
      const unsigned short* wr = &ws[WS_WIH + (cb + ni * 16 + l15) * 128 + k];
      const bf16x8 br = *reinterpret_cast<const bf16x8*>(wr);
      const bf16x8 bz = *reinterpret_cast<const bf16x8*>(wr + 256 * 128);
      const bf16x8 bn = *reinterpret_cast<const bf16x8*>(wr + 512 * 128);
#pragma unroll
      for (int mi = 0; mi < 4; ++mi) {
        aR[mi][ni] = MFMA(a[mi], br, aR[mi][ni]);
        aZ[mi][ni] = MFMA(a[mi], bz, aZ[mi][ni]);
        aIN[mi][ni] = MFMA(a[mi], bn, aIN[mi][ni]);
      }
    }
  }
  // gh: K=256 over hs (LDS)
#pragma unroll
  for (int ks = 0; ks < 8; ++ks) {
    const int k = ks * 32 + koff;
    bf16x8 a[4];
#pragma unroll
    for (int mi = 0; mi < 4; ++mi)
      a[mi] = *reinterpret_cast<const bf16x8*>(&hs[mi * 16 + l15][k]);
#pragma unroll
    for (int ni = 0; ni < 2; ++ni) {
      const unsigned short* wr = &ws[WS_WHH + (cb + ni * 16 + l15) * 256 + k];
      const bf16x8 br = *reinterpret_cast<const bf16x8*>(wr);
      const bf16x8 bz = *reinterpret_cast<const bf16x8*>(wr + 256 * 256);
      const bf16x8 bn = *reinterpret_cast<const bf16x8*>(wr + 512 * 256);
#pragma unroll
      for (int mi = 0; mi < 4; ++mi) {
        aR[mi][ni] = MFMA(a[mi], br, aR[mi][ni]);
        aZ[mi][ni] = MFMA(a[mi], bz, aZ[mi][ni]);
        aHN[mi][ni] = MFMA(a[mi], bn, aHN[mi][ni]);
      }
    }
  }

  __syncthreads();  // all waves done reading xp before h_new overwrites it

  // epilogue: gate math (f32), h_new store, pred partials
  float ps[4][4] = {};
#pragma unroll
  for (int mi = 0; mi < 4; ++mi) {
#pragma unroll
    for (int ni = 0; ni < 2; ++ni) {
      const int col = cb + ni * 16 + l15;
      const float wh = Whead[col];
#pragma unroll
      for (int r = 0; r < 4; ++r) {
        const int row = mi * 16 + l4 * 4 + r;
        const float rg = 1.f / (1.f + __expf(-aR[mi][ni][r]));
        const float zg = 1.f / (1.f + __expf(-aZ[mi][ni][r]));
        const float e2 = __expf(2.f * (aIN[mi][ni][r] + rg * aHN[mi][ni][r]));
        const float ng = (e2 - 1.f) / (e2 + 1.f);
        const float hv = bf2f(hs[row][col]);
        const float hn = (1.f - zg) * ng + zg * hv;
        out[(size_t)B_N + (size_t)(b0 + row) * H_N + col] = hn;
        ps[mi][r] += hn * wh;
      }
    }
  }
#pragma unroll
  for (int mi = 0; mi < 4; ++mi)
#pragma unroll
    for (int r = 0; r < 4; ++r) {
      float s = ps[mi][r];
      s += __shfl_xor(s, 1);
      s += __shfl_xor(s, 2);
      s += __shfl_xor(s, 4);
      s += __shfl_xor(s, 8);
      if (l15 == 0) predp[w][mi * 16 + l4 * 4 + r] = s;
    }
  __syncthreads();

  if (tid < 64) {
    float s = bhead[0];
#pragma unroll
    for (int w2 = 0; w2 < 8; ++w2) s += predp[w2][tid];
    out[b0 + tid] = s;
  }
}

extern "C" void kernel_launch(void* const* d_in, const int* in_sizes, int n_in,
                              void* d_out, int out_size, void* d_ws, size_t ws_size,
                              hipStream_t stream) {
  const float* x     = (const float*)d_in[0];
  const float* h0    = (const float*)d_in[1];
  const float* Wp    = (const float*)d_in[2];
  const float* bp    = (const float*)d_in[3];
  const float* Wih   = (const float*)d_in[4];
  const float* Whh   = (const float*)d_in[5];
  const float* bih   = (const float*)d_in[6];
  const float* bhh   = (const float*)d_in[7];
  const float* Whead = (const float*)d_in[8];
  const float* bhead = (const float*)d_in[9];
  float* out = (float*)d_out;
  unsigned short* ws = (unsigned short*)d_ws;

  cvt_w<<<(WS_TOT + 255) / 256, 256, 0, stream>>>(Wp, Wih, Whh, ws);
  xproj<<<B_N / 64, 256, 0, stream>>>(x, ws, bp, out);
  gru_main<<<B_N / 64, 512, 0, stream>>>(h0, ws, bih, bhh, Whead, bhead, out);
}

// Round 3
// 291.157 us; speedup vs baseline: 1.7448x; 1.7448x over previous
//
#include <hip/hip_runtime.h>

#define B_N 131072
#define IN_N 40
#define P_N 128
#define H_N 256

typedef __bf16 bf16x8 __attribute__((ext_vector_type(8)));
typedef float f32x4 __attribute__((ext_vector_type(4)));

#define MFMA(a, b, c) __builtin_amdgcn_mfma_f32_16x16x32_bf16(a, b, c, 0, 0, 0)

__device__ __forceinline__ unsigned short f2bf(float f) {
  union { float f; unsigned u; } a; a.f = f;
  unsigned u = a.u;
  u += 0x7FFFu + ((u >> 16) & 1u);   // RNE
  return (unsigned short)(u >> 16);
}
__device__ __forceinline__ float bf2f(unsigned short h) {
  union { unsigned u; float f; } a; a.u = ((unsigned)h) << 16;
  return a.f;
}

// ws layout (ushort elements):
//   [0, 8192)            W_proj padded to [128][64] (cols 40..63 zero)
//   [8192, 106496)       W_ih  [768][128]
//   [106496, 303104)     W_hh  [768][256]
#define WS_WP 0
#define WS_WIH 8192
#define WS_WHH (8192 + 98304)
#define WS_TOT (8192 + 98304 + 196608)

__global__ void cvt_w(const float* __restrict__ Wp, const float* __restrict__ Wih,
                      const float* __restrict__ Whh, const float* __restrict__ bhead,
                      unsigned short* __restrict__ ws, float* __restrict__ out) {
  int i = blockIdx.x * 256 + threadIdx.x;
  if (i < 8192) {
    int r = i >> 6, c = i & 63;
    ws[i] = f2bf(c < IN_N ? Wp[r * IN_N + c] : 0.f);
  } else if (i < WS_WHH) {
    ws[i] = f2bf(Wih[i - WS_WIH]);
  } else if (i < WS_TOT) {
    ws[i] = f2bf(Whh[i - WS_WHH]);
  }
  if (i < B_N) out[i] = bhead[0];   // pred init: bias; gru blocks atomicAdd partials
}

// 256 threads = 4 waves. Block: 64 batch rows x 64 H-cols (col-split 4).
// Wave w: 16 H-cols. VGPR target ~130 (acc 64 + frags + addr) -> 3 blocks/CU.
__global__ __launch_bounds__(256, 3) void gru_fused(
    const float* __restrict__ x, const float* __restrict__ h0,
    const unsigned short* __restrict__ ws,
    const float* __restrict__ bp, const float* __restrict__ bih,
    const float* __restrict__ bhh, const float* __restrict__ Whead,
    float* __restrict__ out) {
  __shared__ unsigned short hs[64][264];   // 33792 B; row stride 528B -> 2-way alias (free)
  __shared__ unsigned char uni[18432];     // union: xs (phaseA) | xp+predp (phaseB)
  unsigned short (*xs)[72] = (unsigned short(*)[72])uni;
  unsigned short (*xp)[136] = (unsigned short(*)[136])uni;
  float* predp = (float*)(uni + 17408);    // [4][64]

  const int tid = threadIdx.x;
  // XCD swizzle: same-XCD blocks get contiguous t -> 4 col-siblings + adjacent
  // row tiles share L2 for h.
  const int t = (blockIdx.x & 7) * 1024 + (blockIdx.x >> 3);
  const int ch = t & 3;                    // column quarter
  const int b0 = (t >> 2) * 64;            // batch row base
  const int lane = tid & 63;
  const int w = tid >> 6;                  // wave 0..3
  const int l15 = lane & 15;
  const int l4 = lane >> 4;                // 0..3
  const int koff = l4 * 8;

  // ---- stage h (f32 -> bf16) and x (bf16, zero-pad K 40->64) ----
  for (int i = tid; i < 64 * 64; i += 256) {
    int r = i >> 6, c4 = (i & 63) * 4;
    float4 v = *reinterpret_cast<const float4*>(&h0[(size_t)(b0 + r) * H_N + c4]);
    ushort4 u;
    u.x = f2bf(v.x); u.y = f2bf(v.y); u.z = f2bf(v.z); u.w = f2bf(v.w);
    *reinterpret_cast<ushort4*>(&hs[r][c4]) = u;
  }
  for (int i = tid; i < 64 * 24; i += 256) {
    int r = i / 24, c = 40 + i % 24;
    xs[r][c] = 0;
  }
  for (int i = tid; i < 64 * 40; i += 256) {
    int r = i / 40, c = i % 40;
    xs[r][c] = f2bf(x[(size_t)b0 * IN_N + i]);
  }
  __syncthreads();

  // ---- xproj: wave w owns P-cols w*32 .. w*32+31 ----
  f32x4 px[4][2] = {};
#pragma unroll
  for (int ks = 0; ks < 2; ++ks) {
    const int k = ks * 32 + koff;
    bf16x8 a[4];
#pragma unroll
    for (int mi = 0; mi < 4; ++mi)
      a[mi] = *reinterpret_cast<const bf16x8*>(&xs[mi * 16 + l15][k]);
#pragma unroll
    for (int ni = 0; ni < 2; ++ni) {
      const bf16x8 b = *reinterpret_cast<const bf16x8*>(
          &ws[WS_WP + (w * 32 + ni * 16 + l15) * 64 + k]);
#pragma unroll
      for (int mi = 0; mi < 4; ++mi)
        px[mi][ni] = MFMA(a[mi], b, px[mi][ni]);
    }
  }
  __syncthreads();  // all xs reads complete before xp overwrites the union

#pragma unroll
  for (int ni = 0; ni < 2; ++ni) {
    const int pc = w * 32 + ni * 16 + l15;
    const float bias = bp[pc];
#pragma unroll
    for (int mi = 0; mi < 4; ++mi)
#pragma unroll
      for (int r = 0; r < 4; ++r)
        xp[mi * 16 + l4 * 4 + r][pc] = f2bf(px[mi][ni][r] + bias);
  }
  __syncthreads();

  // ---- gates: wave owns H-cols [ch*64 + w*16, +16) ----
  const int col = ch * 64 + w * 16 + l15;
  f32x4 aR[4], aZ[4], aIN[4], aHN[4];
  {
    const float vR = bih[col] + bhh[col];
    const float vZ = bih[H_N + col] + bhh[H_N + col];
    const float vIN = bih[2 * H_N + col];
    const float vHN = bhh[2 * H_N + col];
#pragma unroll
    for (int mi = 0; mi < 4; ++mi) {
      aR[mi] = (f32x4){vR, vR, vR, vR};
      aZ[mi] = (f32x4){vZ, vZ, vZ, vZ};
      aIN[mi] = (f32x4){vIN, vIN, vIN, vIN};
      aHN[mi] = (f32x4){vHN, vHN, vHN, vHN};
    }
  }
  // gi: K=128 over xp
#pragma unroll
  for (int ks = 0; ks < 4; ++ks) {
    const int k = ks * 32 + koff;
    bf16x8 a[4];
#pragma unroll
    for (int mi = 0; mi < 4; ++mi)
      a[mi] = *reinterpret_cast<const bf16x8*>(&xp[mi * 16 + l15][k]);
    const unsigned short* wr = &ws[WS_WIH + (size_t)col * 128 + k];
    const bf16x8 br = *reinterpret_cast<const bf16x8*>(wr);
    const bf16x8 bz = *reinterpret_cast<const bf16x8*>(wr + 256 * 128);
    const bf16x8 bn = *reinterpret_cast<const bf16x8*>(wr + 512 * 128);
#pragma unroll
    for (int mi = 0; mi < 4; ++mi) {
      aR[mi] = MFMA(a[mi], br, aR[mi]);
      aZ[mi] = MFMA(a[mi], bz, aZ[mi]);
      aIN[mi] = MFMA(a[mi], bn, aIN[mi]);
    }
  }
  // gh: K=256 over hs
#pragma unroll
  for (int ks = 0; ks < 8; ++ks) {
    const int k = ks * 32 + koff;
    bf16x8 a[4];
#pragma unroll
    for (int mi = 0; mi < 4; ++mi)
      a[mi] = *reinterpret_cast<const bf16x8*>(&hs[mi * 16 + l15][k]);
    const unsigned short* wr = &ws[WS_WHH + (size_t)col * 256 + k];
    const bf16x8 br = *reinterpret_cast<const bf16x8*>(wr);
    const bf16x8 bz = *reinterpret_cast<const bf16x8*>(wr + 256 * 256);
    const bf16x8 bn = *reinterpret_cast<const bf16x8*>(wr + 512 * 256);
#pragma unroll
    for (int mi = 0; mi < 4; ++mi) {
      aR[mi] = MFMA(a[mi], br, aR[mi]);
      aZ[mi] = MFMA(a[mi], bz, aZ[mi]);
      aHN[mi] = MFMA(a[mi], bn, aHN[mi]);
    }
  }

  // ---- epilogue: gates (f32), h_new store, pred partials ----
  const float wh = Whead[col];
  float ps[4][4] = {};
#pragma unroll
  for (int mi = 0; mi < 4; ++mi) {
#pragma unroll
    for (int r = 0; r < 4; ++r) {
      const int row = mi * 16 + l4 * 4 + r;
      const float rg = 1.f / (1.f + __expf(-aR[mi][r]));
      const float zg = 1.f / (1.f + __expf(-aZ[mi][r]));
      const float e2 = __expf(2.f * (aIN[mi][r] + rg * aHN[mi][r]));
      const float ng = (e2 - 1.f) / (e2 + 1.f);
      const float hv = bf2f(hs[row][col]);
      const float hn = (1.f - zg) * ng + zg * hv;
      out[(size_t)B_N + (size_t)(b0 + row) * H_N + col] = hn;
      ps[mi][r] += hn * wh;
    }
  }
#pragma unroll
  for (int mi = 0; mi < 4; ++mi)
#pragma unroll
    for (int r = 0; r < 4; ++r) {
      float s = ps[mi][r];
      s += __shfl_xor(s, 1);
      s += __shfl_xor(s, 2);
      s += __shfl_xor(s, 4);
      s += __shfl_xor(s, 8);
      if (l15 == 0) predp[w * 64 + mi * 16 + l4 * 4 + r] = s;
    }
  __syncthreads();

  if (tid < 64) {
    float s = predp[tid] + predp[64 + tid] + predp[128 + tid] + predp[192 + tid];
    atomicAdd(&out[b0 + tid], s);   // 4 col-quarters/row; init = bhead (cvt_w)
  }
}

extern "C" void kernel_launch(void* const* d_in, const int* in_sizes, int n_in,
                              void* d_out, int out_size, void* d_ws, size_t ws_size,
                              hipStream_t stream) {
  const float* x     = (const float*)d_in[0];
  const float* h0    = (const float*)d_in[1];
  const float* Wp    = (const float*)d_in[2];
  const float* bp    = (const float*)d_in[3];
  const float* Wih   = (const float*)d_in[4];
  const float* Whh   = (const float*)d_in[5];
  const float* bih   = (const float*)d_in[6];
  const float* bhh   = (const float*)d_in[7];
  const float* Whead = (const float*)d_in[8];
  const float* bhead = (const float*)d_in[9];
  float* out = (float*)d_out;
  unsigned short* ws = (unsigned short*)d_ws;

  cvt_w<<<(WS_TOT + 255) / 256, 256, 0, stream>>>(Wp, Wih, Whh, bhead, ws, out);
  gru_fused<<<(B_N / 64) * 4, 256, 0, stream>>>(x, h0, ws, bp, bih, bhh, Whead, out);
}